// Round 2
// baseline (98.343 us; speedup 1.0000x reference)
//
#include <hip/hip_runtime.h>
#include <hip/hip_bf16.h>

#define N 8192
#define D 256

typedef __bf16 bf16x8 __attribute__((ext_vector_type(8)));
typedef float f32x4 __attribute__((ext_vector_type(4)));
typedef float f32x16 __attribute__((ext_vector_type(16)));

static __device__ __forceinline__ unsigned short f2bf(float x) {
    union { float f; unsigned int u; } c; c.f = x;
    unsigned int r = (c.u + 0x7fffu + ((c.u >> 16) & 1u)) >> 16;
    return (unsigned short)r;
}

static __device__ __forceinline__ void gll16(const void* g, void* l) {
    __builtin_amdgcn_global_load_lds(
        (const __attribute__((address_space(1))) void*)g,
        (__attribute__((address_space(3))) void*)l, 16, 0, 0);
}

// =====================================================================
// NEW PATH: pre-convert to normalized, pre-swizzled bf16; GEMM via
// global_load_lds staging + 32x32x16 MFMA, 64x64 wave tiles.
// =====================================================================
#define SP2 4
#define CPB (N / SP2)          // 2048 cols per block
#define BNC 256                // cols per B tile
#define NJT (CPB / BNC)        // 8
#define NPH (NJT * 2)          // 16 half-K phases

// one wave per row: norms, diag, normalized bf16 write with global pre-swizzle
__global__ __launch_bounds__(256) void conv_k(const float* __restrict__ o1,
                                              const float* __restrict__ o2,
                                              unsigned char* __restrict__ a_bf,
                                              unsigned char* __restrict__ b_bf,
                                              float* __restrict__ diag) {
    const int wid = threadIdx.x >> 6, lane = threadIdx.x & 63;
    const int r = blockIdx.x * 4 + wid;
    const float4* p1 = (const float4*)(o1 + (size_t)r * D);
    const float4* p2 = (const float4*)(o2 + (size_t)r * D);
    float4 v1 = p1[lane], v2 = p2[lane];
    float s1 = v1.x*v1.x + v1.y*v1.y + v1.z*v1.z + v1.w*v1.w;
    float s2 = v2.x*v2.x + v2.y*v2.y + v2.z*v2.z + v2.w*v2.w;
    float sd = v1.x*v2.x + v1.y*v2.y + v1.z*v2.z + v1.w*v2.w;
    #pragma unroll
    for (int m = 1; m < 64; m <<= 1) {
        s1 += __shfl_xor(s1, m);
        s2 += __shfl_xor(s2, m);
        sd += __shfl_xor(sd, m);
    }
    float i1 = 1.0f / sqrtf(s1);
    float i2 = 1.0f / sqrtf(s2);
    if (lane == 0) diag[r] = sd * i1 * i2;

    // A: 512B rows, 32 chunks of 16B, chunk c -> c ^ (r&31)
    {
        unsigned int lo = (unsigned int)f2bf(v1.x * i1) | ((unsigned int)f2bf(v1.y * i1) << 16);
        unsigned int hi = (unsigned int)f2bf(v1.z * i1) | ((unsigned int)f2bf(v1.w * i1) << 16);
        int c  = lane >> 1;                 // 0..31
        int cs = c ^ (r & 31);
        uint2 q; q.x = lo; q.y = hi;
        *(uint2*)(a_bf + (size_t)r * 512 + cs * 16 + (lane & 1) * 8) = q;
    }
    // B: 512B rows as two 256B half-K blocks; 16 chunks, chunk c -> c ^ (r&15)
    {
        unsigned int lo = (unsigned int)f2bf(v2.x * i2) | ((unsigned int)f2bf(v2.y * i2) << 16);
        unsigned int hi = (unsigned int)f2bf(v2.z * i2) | ((unsigned int)f2bf(v2.w * i2) << 16);
        int kh = lane >> 5;                 // k-half
        int c  = (lane & 31) >> 1;          // 0..15
        int cs = c ^ (r & 15);
        uint2 q; q.x = lo; q.y = hi;
        *(uint2*)(b_bf + (size_t)r * 512 + kh * 256 + cs * 16 + (lane & 1) * 8) = q;
    }
}

__global__ __launch_bounds__(512, 2) void gemm2(const unsigned char* __restrict__ a_bf,
                                                const unsigned char* __restrict__ b_bf,
                                                float* __restrict__ s_part) {
    __shared__ __align__(16) unsigned char a_lds[128 * 512];  // 64 KB, full K
    __shared__ __align__(16) unsigned char b_lds[256 * 256];  // 64 KB, half K
    __shared__ float red[4][128];

    const int tid = threadIdx.x;
    const int lane = tid & 63, wid = tid >> 6;
    const int wr = wid >> 2, wc = wid & 3;          // 2 x 4 wave grid
    const int l31 = lane & 31, lhi = lane >> 5;
    const int rb = blockIdx.x, sp = blockIdx.y;

    const unsigned char* aG = a_bf + (size_t)rb * (128 * 512);
    const unsigned char* bG = b_bf + (size_t)sp * ((size_t)CPB * 512);

    // prologue: stage A (full K) + B phase 0 (cols 0..255, kh=0)
    #pragma unroll
    for (int it = 0; it < 8; ++it) {
        int x = it * 8192 + tid * 16;
        gll16(aG + x, a_lds + x);
        gll16(bG + (size_t)(x >> 8) * 512 + (x & 255), b_lds + x);
    }
    __syncthreads();

    float srow[2][16];
    #pragma unroll
    for (int mr = 0; mr < 2; ++mr)
        #pragma unroll
        for (int r = 0; r < 16; ++r) srow[mr][r] = 0.f;

    f32x16 acc[2][2];

    for (int jt = 0; jt < NJT; ++jt) {
        #pragma unroll
        for (int kh = 0; kh < 2; ++kh) {
            const int ph = jt * 2 + kh;
            const bool more = (ph + 1) < NPH;
            // T14: prefetch next B half-tile to registers (latency hides under MFMA)
            uint4 pre[8];
            if (more) {
                const int nc0 = ((ph + 1) >> 1) * BNC;
                const int nkh = (ph + 1) & 1;
                #pragma unroll
                for (int it = 0; it < 8; ++it) {
                    int x = it * 8192 + tid * 16;
                    pre[it] = *(const uint4*)(bG + (size_t)(nc0 + (x >> 8)) * 512
                                                 + nkh * 256 + (x & 255));
                }
            }
            if (kh == 0) {
                #pragma unroll
                for (int mr = 0; mr < 2; ++mr)
                    #pragma unroll
                    for (int nc = 0; nc < 2; ++nc)
                        #pragma unroll
                        for (int r = 0; r < 16; ++r) acc[mr][nc][r] = 0.f;
            }
            #pragma unroll
            for (int ks = 0; ks < 8; ++ks) {
                bf16x8 af[2], bb[2];
                const int kbA = kh * 256 + ks * 32 + lhi * 16;
                const int csA = (kbA >> 4) ^ l31;          // row&31 == l31
                #pragma unroll
                for (int mr = 0; mr < 2; ++mr) {
                    int row = wr * 64 + mr * 32 + l31;
                    af[mr] = *(const bf16x8*)(a_lds + row * 512 + csA * 16);
                }
                const int kbB = ks * 32 + lhi * 16;
                const int csB = (kbB >> 4) ^ (l31 & 15);   // col&15 == l31&15
                #pragma unroll
                for (int nc = 0; nc < 2; ++nc) {
                    int col = wc * 64 + nc * 32 + l31;
                    bb[nc] = *(const bf16x8*)(b_lds + col * 256 + csB * 16);
                }
                #pragma unroll
                for (int mr = 0; mr < 2; ++mr)
                    #pragma unroll
                    for (int nc = 0; nc < 2; ++nc)
                        acc[mr][nc] = __builtin_amdgcn_mfma_f32_32x32x16_bf16(
                            af[mr], bb[nc], acc[mr][nc], 0, 0, 0);
            }
            if (kh == 1) {
                // cos bounded by ~1 -> no running max needed
                #pragma unroll
                for (int mr = 0; mr < 2; ++mr)
                    #pragma unroll
                    for (int r = 0; r < 16; ++r)
                        srow[mr][r] += __expf(acc[mr][0][r]) + __expf(acc[mr][1][r]);
            }
            __syncthreads();             // all waves done reading b_lds
            if (more) {
                #pragma unroll
                for (int it = 0; it < 8; ++it) {
                    int x = it * 8192 + tid * 16;
                    *(uint4*)(b_lds + x) = pre[it];
                }
            }
            __syncthreads();             // next B half ready
        }
    }

    // reduce across the 32 column-lanes (C layout: col = lane&31)
    #pragma unroll
    for (int mr = 0; mr < 2; ++mr)
        #pragma unroll
        for (int r = 0; r < 16; ++r) {
            float v = srow[mr][r];
            v += __shfl_xor(v, 1);
            v += __shfl_xor(v, 2);
            v += __shfl_xor(v, 4);
            v += __shfl_xor(v, 8);
            v += __shfl_xor(v, 16);
            srow[mr][r] = v;
        }
    if (l31 == 0) {
        #pragma unroll
        for (int mr = 0; mr < 2; ++mr)
            #pragma unroll
            for (int r = 0; r < 16; ++r) {
                int rl = wr * 64 + mr * 32 + 4 * lhi + (r & 3) + 8 * (r >> 2);
                red[wc][rl] = srow[mr][r];
            }
    }
    __syncthreads();
    if (tid < 128) {
        float s = red[0][tid] + red[1][tid] + red[2][tid] + red[3][tid];
        s_part[(size_t)sp * N + rb * 128 + tid] = s;
    }
}

__global__ __launch_bounds__(128) void rowloss2(const float* __restrict__ s_part,
                                                const float* __restrict__ diag,
                                                float* __restrict__ partial) {
    const int t = threadIdx.x, rb = blockIdx.x;
    float s = 0.f;
    #pragma unroll
    for (int sp = 0; sp < SP2; ++sp)
        s += s_part[(size_t)sp * N + rb * 128 + t];
    float loss = logf(s) - diag[rb * 128 + t];
    #pragma unroll
    for (int m = 1; m < 64; m <<= 1) loss += __shfl_xor(loss, m);
    __shared__ float redl[2];
    if ((t & 63) == 0) redl[t >> 6] = loss;
    __syncthreads();
    if (t == 0) partial[rb] = redl[0] + redl[1];
}

__global__ __launch_bounds__(64) void final_k(const float* __restrict__ partial,
                                              float* __restrict__ out) {
    const int t = threadIdx.x;
    float v = partial[t];
    #pragma unroll
    for (int m = 1; m < 64; m <<= 1) v += __shfl_xor(v, m);
    if (t == 0) out[0] = v / (float)N;
}

// =====================================================================
// FALLBACK PATH (round-1, passed): used only if ws_size is too small.
// =====================================================================
#define BM 128
#define BN 128
#define SPLIT 16
#define JTILES ((N / SPLIT) / BN)

__global__ __launch_bounds__(256) void norms_fb(const float* __restrict__ o1,
                                                const float* __restrict__ o2,
                                                float* __restrict__ inv1,
                                                float* __restrict__ inv2,
                                                float* __restrict__ diag) {
    const int wid = threadIdx.x >> 6, lane = threadIdx.x & 63;
    const int r = blockIdx.x * 4 + wid;
    const float4* p1 = (const float4*)(o1 + (size_t)r * D);
    const float4* p2 = (const float4*)(o2 + (size_t)r * D);
    float4 v1 = p1[lane], v2 = p2[lane];
    float s1 = v1.x*v1.x + v1.y*v1.y + v1.z*v1.z + v1.w*v1.w;
    float s2 = v2.x*v2.x + v2.y*v2.y + v2.z*v2.z + v2.w*v2.w;
    float sd = v1.x*v2.x + v1.y*v2.y + v1.z*v2.z + v1.w*v2.w;
    #pragma unroll
    for (int m = 1; m < 64; m <<= 1) {
        s1 += __shfl_xor(s1, m);
        s2 += __shfl_xor(s2, m);
        sd += __shfl_xor(sd, m);
    }
    if (lane == 0) {
        float i1 = 1.0f / sqrtf(s1);
        float i2 = 1.0f / sqrtf(s2);
        inv1[r] = i1; inv2[r] = i2;
        diag[r] = sd * i1 * i2;
    }
}

static __device__ __forceinline__ void stage_fb(const float* __restrict__ src,
                                                const float* __restrict__ inv,
                                                int r0, unsigned short* lds, int tid) {
    const float4* s4 = (const float4*)(src + (size_t)r0 * D);
    #pragma unroll
    for (int it = 0; it < (BM * D / 4) / 512; ++it) {
        int idx = it * 512 + tid;
        int row = idx >> 6, c4 = idx & 63;
        float4 v = s4[idx];
        float sc = inv[r0 + row];
        unsigned int lo = (unsigned int)f2bf(v.x * sc) | ((unsigned int)f2bf(v.y * sc) << 16);
        unsigned int hi = (unsigned int)f2bf(v.z * sc) | ((unsigned int)f2bf(v.w * sc) << 16);
        int byte = row * 512 + ((c4 * 8) ^ ((row & 7) << 4));
        uint2 q; q.x = lo; q.y = hi;
        *(uint2*)((char*)lds + byte) = q;
    }
}

__global__ __launch_bounds__(512) void gemm_fb(const float* __restrict__ o1,
                                               const float* __restrict__ o2,
                                               const float* __restrict__ inv1,
                                               const float* __restrict__ inv2,
                                               float* __restrict__ s_part) {
    __shared__ unsigned short a_lds[BM * D];
    __shared__ unsigned short b_lds[BN * D];
    __shared__ float lds_s[4][BM];

    const int tid = threadIdx.x;
    const int lane = tid & 63, wid = tid >> 6;
    const int wr = wid >> 2, wc = wid & 3;
    const int rb = blockIdx.x, sp = blockIdx.y;
    const int i0 = rb * BM, j0 = sp * (N / SPLIT);

    stage_fb(o1, inv1, i0, a_lds, tid);

    float srow[4][4];
    #pragma unroll
    for (int a = 0; a < 4; ++a)
        #pragma unroll
        for (int b = 0; b < 4; ++b) srow[a][b] = 0.f;

    const int kx = (lane >> 4) * 16;

    for (int jt = 0; jt < JTILES; ++jt) {
        __syncthreads();
        stage_fb(o2, inv2, j0 + jt * BN, b_lds, tid);
        __syncthreads();

        f32x4 acc[4][2];
        #pragma unroll
        for (int mr = 0; mr < 4; ++mr)
            #pragma unroll
            for (int nc = 0; nc < 2; ++nc)
                acc[mr][nc] = (f32x4){0.f, 0.f, 0.f, 0.f};

        #pragma unroll
        for (int ko = 0; ko < 8; ++ko) {
            bf16x8 af[4], bfr[2];
            #pragma unroll
            for (int mr = 0; mr < 4; ++mr) {
                int r = wr * 64 + mr * 16 + (lane & 15);
                int off = r * 512 + ((ko * 64 + kx) ^ ((r & 7) << 4));
                af[mr] = *(const bf16x8*)((const char*)a_lds + off);
            }
            #pragma unroll
            for (int nc = 0; nc < 2; ++nc) {
                int c = wc * 32 + nc * 16 + (lane & 15);
                int off = c * 512 + ((ko * 64 + kx) ^ ((c & 7) << 4));
                bfr[nc] = *(const bf16x8*)((const char*)b_lds + off);
            }
            #pragma unroll
            for (int mr = 0; mr < 4; ++mr)
                #pragma unroll
                for (int nc = 0; nc < 2; ++nc)
                    acc[mr][nc] = __builtin_amdgcn_mfma_f32_16x16x32_bf16(
                        af[mr], bfr[nc], acc[mr][nc], 0, 0, 0);
        }

        #pragma unroll
        for (int mr = 0; mr < 4; ++mr)
            #pragma unroll
            for (int nc = 0; nc < 2; ++nc)
                #pragma unroll
                for (int rg = 0; rg < 4; ++rg)
                    srow[mr][rg] += __expf(acc[mr][nc][rg]);
    }

    #pragma unroll
    for (int mr = 0; mr < 4; ++mr)
        #pragma unroll
        for (int rg = 0; rg < 4; ++rg) {
            float v = srow[mr][rg];
            v += __shfl_xor(v, 1);
            v += __shfl_xor(v, 2);
            v += __shfl_xor(v, 4);
            v += __shfl_xor(v, 8);
            srow[mr][rg] = v;
        }

    if ((lane & 15) == 0) {
        int g = lane >> 4;
        #pragma unroll
        for (int mr = 0; mr < 4; ++mr)
            #pragma unroll
            for (int rg = 0; rg < 4; ++rg)
                lds_s[wc][wr * 64 + mr * 16 + g * 4 + rg] = srow[mr][rg];
    }
    __syncthreads();
    if (tid < BM) {
        float s = lds_s[0][tid] + lds_s[1][tid] + lds_s[2][tid] + lds_s[3][tid];
        s_part[(rb * SPLIT + sp) * BM + tid] = s;
    }
}

__global__ __launch_bounds__(128) void rowloss_fb(const float* __restrict__ s_part,
                                                  const float* __restrict__ diag,
                                                  float* __restrict__ partial) {
    const int t = threadIdx.x, rb = blockIdx.x;
    float s = 0.f;
    #pragma unroll
    for (int sp = 0; sp < SPLIT; ++sp)
        s += s_part[(rb * SPLIT + sp) * BM + t];
    float loss = logf(s) - diag[rb * BM + t];
    #pragma unroll
    for (int m = 1; m < 64; m <<= 1) loss += __shfl_xor(loss, m);
    __shared__ float red[2];
    if ((t & 63) == 0) red[t >> 6] = loss;
    __syncthreads();
    if (t == 0) partial[rb] = red[0] + red[1];
}

// =====================================================================
extern "C" void kernel_launch(void* const* d_in, const int* in_sizes, int n_in,
                              void* d_out, int out_size, void* d_ws, size_t ws_size,
                              hipStream_t stream) {
    const float* o1 = (const float*)d_in[0];
    const float* o2 = (const float*)d_in[1];

    const size_t NEED = (size_t)8 * 1024 * 1024 + 32768 + 131072 + 256;
    if (ws_size >= NEED) {
        unsigned char* w = (unsigned char*)d_ws;
        unsigned char* a_bf = w;                                   // 4 MB
        unsigned char* b_bf = w + (size_t)4 * 1024 * 1024;         // 4 MB
        float* diag    = (float*)(w + (size_t)8 * 1024 * 1024);    // 32 KB
        float* s_part  = diag + N;                                 // 128 KB
        float* partial = s_part + (size_t)SP2 * N;                 // 256 B

        conv_k<<<N / 4, 256, 0, stream>>>(o1, o2, a_bf, b_bf, diag);
        dim3 g(N / 128, SP2);
        gemm2<<<g, 512, 0, stream>>>(a_bf, b_bf, s_part);
        rowloss2<<<N / 128, 128, 0, stream>>>(s_part, diag, partial);
        final_k<<<1, 64, 0, stream>>>(partial, (float*)d_out);
    } else {
        float* ws = (float*)d_ws;
        float* inv1    = ws;
        float* inv2    = ws + 8192;
        float* diag    = ws + 16384;
        float* s_part  = ws + 24576;
        float* partial = ws + 24576 + 131072;

        norms_fb<<<N / 4, 256, 0, stream>>>(o1, o2, inv1, inv2, diag);
        dim3 g(N / BM, SPLIT);
        gemm_fb<<<g, 512, 0, stream>>>(o1, o2, inv1, inv2, s_part);
        rowloss_fb<<<N / BM, 128, 0, stream>>>(s_part, diag, partial);
        final_k<<<1, 64, 0, stream>>>(partial, (float*)d_out);
    }
}

// Round 3
// 58.204 us; speedup vs baseline: 1.6896x; 1.6896x over previous
//
#include <hip/hip_runtime.h>
#include <hip/hip_bf16.h>

#define N 8192
#define D 256
#define SP2 4
#define CPB (N / SP2)          // 2048 cols per block
#define NCH 32                 // 16 col-groups x 2 k-halves

typedef __bf16 bf16x8 __attribute__((ext_vector_type(8)));
typedef float f32x16 __attribute__((ext_vector_type(16)));

static __device__ __forceinline__ unsigned short f2bf(float x) {
    union { float f; unsigned int u; } c; c.f = x;
    unsigned int r = (c.u + 0x7fffu + ((c.u >> 16) & 1u)) >> 16;
    return (unsigned short)r;
}

static __device__ __forceinline__ void gll16(const void* g, void* l) {
    __builtin_amdgcn_global_load_lds(
        (const __attribute__((address_space(1))) void*)g,
        (__attribute__((address_space(3))) void*)l, 16, 0, 0);
}

#define WAIT_VM4  asm volatile("s_waitcnt vmcnt(4)" ::: "memory")
#define WAIT_VM0  asm volatile("s_waitcnt vmcnt(0)" ::: "memory")
#define WAIT_LG0  asm volatile("s_waitcnt lgkmcnt(0)" ::: "memory")
#define SBAR      __builtin_amdgcn_s_barrier()
#define SCHED0    __builtin_amdgcn_sched_barrier(0)

// ---------- kernel 1: norms + exact fp32 diag + normalized pre-swizzled bf16 ----------
__global__ __launch_bounds__(256) void conv_k(const float* __restrict__ o1,
                                              const float* __restrict__ o2,
                                              unsigned char* __restrict__ a_bf,
                                              unsigned char* __restrict__ b_bf,
                                              float* __restrict__ diag) {
    const int wid = threadIdx.x >> 6, lane = threadIdx.x & 63;
    const int r = blockIdx.x * 4 + wid;
    const float4* p1 = (const float4*)(o1 + (size_t)r * D);
    const float4* p2 = (const float4*)(o2 + (size_t)r * D);
    float4 v1 = p1[lane], v2 = p2[lane];
    float s1 = v1.x*v1.x + v1.y*v1.y + v1.z*v1.z + v1.w*v1.w;
    float s2 = v2.x*v2.x + v2.y*v2.y + v2.z*v2.z + v2.w*v2.w;
    float sd = v1.x*v2.x + v1.y*v2.y + v1.z*v2.z + v1.w*v2.w;
    #pragma unroll
    for (int m = 1; m < 64; m <<= 1) {
        s1 += __shfl_xor(s1, m);
        s2 += __shfl_xor(s2, m);
        sd += __shfl_xor(sd, m);
    }
    float i1 = 1.0f / sqrtf(s1);
    float i2 = 1.0f / sqrtf(s2);
    if (lane == 0) diag[r] = sd * i1 * i2;

    // A: 512B rows, 32 chunks of 16B, chunk c -> c ^ (r&31)
    {
        unsigned int lo = (unsigned int)f2bf(v1.x * i1) | ((unsigned int)f2bf(v1.y * i1) << 16);
        unsigned int hi = (unsigned int)f2bf(v1.z * i1) | ((unsigned int)f2bf(v1.w * i1) << 16);
        int c  = lane >> 1;
        int cs = c ^ (r & 31);
        uint2 q; q.x = lo; q.y = hi;
        *(uint2*)(a_bf + (size_t)r * 512 + cs * 16 + (lane & 1) * 8) = q;
    }
    // B: two 256B half-K blocks per row; 16 chunks, chunk c -> c ^ (r&15)
    {
        unsigned int lo = (unsigned int)f2bf(v2.x * i2) | ((unsigned int)f2bf(v2.y * i2) << 16);
        unsigned int hi = (unsigned int)f2bf(v2.z * i2) | ((unsigned int)f2bf(v2.w * i2) << 16);
        int kh = lane >> 5;
        int c  = (lane & 31) >> 1;
        int cs = c ^ (r & 15);
        uint2 q; q.x = lo; q.y = hi;
        *(uint2*)(b_bf + (size_t)r * 512 + kh * 256 + cs * 16 + (lane & 1) * 8) = q;
    }
}

// ---------- kernel 2: pipelined bf16 GEMM + row-wise sum(exp) ----------
#define STAGE_B(T, BBUF)                                                        \
    {                                                                           \
        const int c0_  = ((T) >> 1) * 128;                                      \
        const int khh_ = (T) & 1;                                               \
        _Pragma("unroll")                                                       \
        for (int it = 0; it < 4; ++it) {                                        \
            int x_ = it * 8192 + tid * 16;                                      \
            int col_ = x_ >> 8, off_ = x_ & 255;                                \
            gll16(bG + (size_t)(c0_ + col_) * 512 + khh_ * 256 + off_,          \
                  BBUF + x_);                                                   \
        }                                                                       \
    }

#define COMPUTE(BBUF, KH)                                                       \
    {                                                                           \
        _Pragma("unroll")                                                       \
        for (int ks = 0; ks < 8; ++ks) {                                        \
            const int kb_  = (KH) * 256 + ks * 32 + lhi * 16;                   \
            const int csA_ = (kb_ >> 4) ^ l31;                                  \
            bf16x8 af0 = *(const bf16x8*)(a_lds + (wr * 64 + l31) * 512 + csA_ * 16);       \
            bf16x8 af1 = *(const bf16x8*)(a_lds + (wr * 64 + 32 + l31) * 512 + csA_ * 16);  \
            const int csB_ = ((ks * 32 + lhi * 16) >> 4) ^ (l31 & 15);          \
            bf16x8 bb = *(const bf16x8*)(BBUF + (wc * 32 + l31) * 256 + csB_ * 16);         \
            acc0 = __builtin_amdgcn_mfma_f32_32x32x16_bf16(af0, bb, acc0, 0, 0, 0);         \
            acc1 = __builtin_amdgcn_mfma_f32_32x32x16_bf16(af1, bb, acc1, 0, 0, 0);         \
        }                                                                       \
    }

__global__ __launch_bounds__(512, 1) void gemm3(const unsigned char* __restrict__ a_bf,
                                                const unsigned char* __restrict__ b_bf,
                                                float* __restrict__ s_part) {
    __shared__ __align__(16) unsigned char a_lds[128 * 512];    // 64 KB, full K
    __shared__ __align__(16) unsigned char b_lds0[128 * 256];   // 32 KB
    __shared__ __align__(16) unsigned char b_lds1[128 * 256];   // 32 KB
    __shared__ float red[4][128];

    const int tid = threadIdx.x;
    const int lane = tid & 63, wid = tid >> 6;
    const int wr = wid >> 2, wc = wid & 3;          // 2 x 4 wave grid
    const int l31 = lane & 31, lhi = lane >> 5;

    // XCD-aware decode: 2 XCDs per sp-panel, 32 rb-blocks each
    const int bid = blockIdx.x;
    const int sp = (bid & 7) >> 1;
    const int rb = (bid >> 3) + 32 * (bid & 1);

    const unsigned char* aG = a_bf + (size_t)rb * (128 * 512);
    const unsigned char* bG = b_bf + (size_t)sp * ((size_t)CPB * 512);

    // prologue: A (full K) + chunk0 -> buf0 + chunk1 -> buf1
    #pragma unroll
    for (int it = 0; it < 8; ++it) {
        int x = it * 8192 + tid * 16;
        gll16(aG + x, a_lds + x);
    }
    STAGE_B(0, b_lds0);
    STAGE_B(1, b_lds1);
    WAIT_VM4;          // A + chunk0 landed; chunk1 in flight
    SCHED0;
    SBAR;

    float srow0[16], srow1[16];
    #pragma unroll
    for (int r = 0; r < 16; ++r) { srow0[r] = 0.f; srow1[r] = 0.f; }

    f32x16 acc0, acc1;

    #pragma unroll 1
    for (int jc = 0; jc < 16; ++jc) {
        // ---- phase 0: chunk 2jc (kh=0, buf0) ----
        #pragma unroll
        for (int r = 0; r < 16; ++r) { acc0[r] = 0.f; acc1[r] = 0.f; }
        __builtin_amdgcn_s_setprio(1);
        COMPUTE(b_lds0, 0);
        __builtin_amdgcn_s_setprio(0);
        WAIT_LG0; SCHED0;
        SBAR;                                    // all waves done reading buf0
        if (jc < 15) {
            STAGE_B(2 * jc + 2, b_lds0);
            WAIT_VM4;                            // chunk 2jc+1 landed
        } else {
            WAIT_VM0;                            // last chunk (31) landed
        }
        SCHED0;
        SBAR;                                    // buf1 ready for everyone

        // ---- phase 1: chunk 2jc+1 (kh=1, buf1) ----
        __builtin_amdgcn_s_setprio(1);
        COMPUTE(b_lds1, 1);
        __builtin_amdgcn_s_setprio(0);
        #pragma unroll
        for (int r = 0; r < 16; ++r) {
            srow0[r] += __expf(acc0[r]);
            srow1[r] += __expf(acc1[r]);
        }
        WAIT_LG0; SCHED0;
        SBAR;                                    // all waves done reading buf1
        if (jc < 15) {
            STAGE_B(2 * jc + 3, b_lds1);
            WAIT_VM4;                            // chunk 2jc+2 landed
        }
        SCHED0;
        SBAR;                                    // buf0 ready for everyone
    }

    // reduce across the 32 column-lanes (C layout: col = lane&31)
    #pragma unroll
    for (int r = 0; r < 16; ++r) {
        float v0 = srow0[r], v1 = srow1[r];
        #pragma unroll
        for (int m = 1; m < 32; m <<= 1) {
            v0 += __shfl_xor(v0, m);
            v1 += __shfl_xor(v1, m);
        }
        srow0[r] = v0; srow1[r] = v1;
    }
    if (l31 == 0) {
        #pragma unroll
        for (int r = 0; r < 16; ++r) {
            int rl = wr * 64 + 4 * lhi + (r & 3) + 8 * (r >> 2);
            red[wc][rl]      = srow0[r];
            red[wc][rl + 32] = srow1[r];
        }
    }
    __syncthreads();
    if (tid < 128) {
        float s = red[0][tid] + red[1][tid] + red[2][tid] + red[3][tid];
        s_part[(size_t)sp * N + rb * 128 + tid] = s;
    }
}

// ---------- kernel 3: per-row loss ----------
__global__ __launch_bounds__(128) void rowloss2(const float* __restrict__ s_part,
                                                const float* __restrict__ diag,
                                                float* __restrict__ partial) {
    const int t = threadIdx.x, rb = blockIdx.x;
    float s = 0.f;
    #pragma unroll
    for (int sp = 0; sp < SP2; ++sp)
        s += s_part[(size_t)sp * N + rb * 128 + t];
    float loss = logf(s) - diag[rb * 128 + t];
    #pragma unroll
    for (int m = 1; m < 64; m <<= 1) loss += __shfl_xor(loss, m);
    __shared__ float redl[2];
    if ((t & 63) == 0) redl[t >> 6] = loss;
    __syncthreads();
    if (t == 0) partial[rb] = redl[0] + redl[1];
}

// ---------- kernel 4: final mean ----------
__global__ __launch_bounds__(64) void final_k(const float* __restrict__ partial,
                                              float* __restrict__ out) {
    const int t = threadIdx.x;
    float v = partial[t];
    #pragma unroll
    for (int m = 1; m < 64; m <<= 1) v += __shfl_xor(v, m);
    if (t == 0) out[0] = v / (float)N;
}

extern "C" void kernel_launch(void* const* d_in, const int* in_sizes, int n_in,
                              void* d_out, int out_size, void* d_ws, size_t ws_size,
                              hipStream_t stream) {
    const float* o1 = (const float*)d_in[0];
    const float* o2 = (const float*)d_in[1];

    unsigned char* w = (unsigned char*)d_ws;
    unsigned char* a_bf = w;                                   // 4 MB
    unsigned char* b_bf = w + (size_t)4 * 1024 * 1024;         // 4 MB
    float* diag    = (float*)(w + (size_t)8 * 1024 * 1024);    // 32 KB
    float* s_part  = diag + N;                                 // 128 KB
    float* partial = s_part + (size_t)SP2 * N;                 // 256 B

    conv_k<<<N / 4, 256, 0, stream>>>(o1, o2, a_bf, b_bf, diag);
    gemm3<<<256, 512, 0, stream>>>(a_bf, b_bf, s_part);
    rowloss2<<<N / 128, 128, 0, stream>>>(s_part, diag, partial);
    final_k<<<1, 64, 0, stream>>>(partial, (float*)d_out);
}